// Round 4
// baseline (209.186 us; speedup 1.0000x reference)
//
#include <hip/hip_runtime.h>

#define HW (1024 * 1024)
#define PLANE 8388608   // C * WS * WS = 512 * 16384

typedef _Float16 half4 __attribute__((ext_vector_type(4)));
typedef _Float16 half8 __attribute__((ext_vector_type(8)));
typedef float floatx4 __attribute__((ext_vector_type(4)));

// Phase 1 (one grid, two block roles running concurrently):
//   blocks [0, 4096):    P[src][j] = sum_e W1[e][j]*xs[e][src]   (fp16, px-major)
//   blocks [4096, 6144): write the three iidd planes (inst/row/col) as float4 stores
__global__ __launch_bounds__(256) void prep(
    const float* __restrict__ x,      // (6, 1024, 1024)
    const float* __restrict__ sigma,  // (1, 1024, 1024)
    const float* __restrict__ W1,     // (7, 16)
    const int*   __restrict__ cent,   // (512, 2)
    _Float16* __restrict__ P,         // (1024*1024, 16)
    float* __restrict__ out)
{
    if (blockIdx.x < 4096) {
        const int px = blockIdx.x * 256 + threadIdx.x;
        float g[7];
#pragma unroll
        for (int e = 0; e < 6; ++e) g[e] = x[e * HW + px];
        g[6] = sigma[px];

        half8 lo, hi;
#pragma unroll
        for (int j = 0; j < 16; ++j) {
            float a = 0.0f;
#pragma unroll
            for (int e = 0; e < 7; ++e)
                a = fmaf(g[e], W1[e * 16 + j], a);
            if (j < 8) lo[j] = (_Float16)a; else hi[j - 8] = (_Float16)a;
        }
        *(half8*)(P + (size_t)px * 16)     = lo;
        *(half8*)(P + (size_t)px * 16 + 8) = hi;
    } else {
        const int b   = blockIdx.x - 4096;   // 0..2047: (window, quarter)
        const int w   = b >> 2;
        const int qtr = b & 3;
        const int cy0 = min(max(cent[2 * w], 64), 960) - 64;
        const int cx0 = min(max(cent[2 * w + 1], 64), 960) - 64;
        const float iw = (float)w;
#pragma unroll
        for (int pass = 0; pass < 4; ++pass) {
            const int p = qtr * 4096 + pass * 1024 + threadIdx.x * 4;
            const int n = w * 16384 + p;
            const float row = (float)(cy0 + (p >> 7));
            const float c0  = (float)(cx0 + (p & 127));
            float4 iv = {iw, iw, iw, iw};
            float4 rv = {row, row, row, row};
            float4 cv = {c0, c0 + 1.0f, c0 + 2.0f, c0 + 3.0f};
            *(float4*)(out + PLANE + n)     = iv;
            *(float4*)(out + 2 * PLANE + n) = rv;
            *(float4*)(out + 3 * PLANE + n) = cv;
        }
    }
}

// Phase 2: h1 = relu(P[src] - q[cid]); h2 = relu(W2^T h1 + b2) via MFMA;
//          prob = sigmoid(W3.h2 + b3). Writes ONLY the prob plane.
__global__ __launch_bounds__(256) void instanseg_mlp(
    const _Float16* __restrict__ P,   // (1024*1024, 16)
    const float* __restrict__ c,      // (512, 6)
    const float* __restrict__ W1,     // (7, 16)
    const float* __restrict__ b1,     // (16)
    const float* __restrict__ W2,     // (16, 16)
    const float* __restrict__ b2,     // (16)
    const float* __restrict__ W3,     // (16, 1)
    const float* __restrict__ b3,     // (1)
    const int*   __restrict__ cent,   // (512, 2)
    float* __restrict__ out)
{
    const int cid  = blockIdx.y;
    const int lane = threadIdx.x & 63;
    const int wave = threadIdx.x >> 6;
    const int quad = lane >> 4;
    const int sub  = lane & 15;

    const int cy0 = min(max(cent[2 * cid], 64), 960) - 64;
    const int cx0 = min(max(cent[2 * cid + 1], 64), 960) - 64;

    // A-fragment: A[m=sub][k=4*quad+i] = W2[k][m];  q = W1_x^T c - b1 (fp16)
    half4 a2, qh;
    float w3f[4], bb2[4];
#pragma unroll
    for (int i = 0; i < 4; ++i) {
        const int k = 4 * quad + i;
        a2[i]  = (_Float16)W2[k * 16 + sub];
        w3f[i] = W3[k];
        bb2[i] = b2[k];
        float qv = -b1[k];
#pragma unroll
        for (int e = 0; e < 6; ++e)
            qv = fmaf(W1[e * 16 + k], c[cid * 6 + e], qv);
        qh[i] = (_Float16)qv;
    }
    const float b3v = b3[0];
    const floatx4 zero = {0.0f, 0.0f, 0.0f, 0.0f};
    const int wavestart = blockIdx.x * 2048 + wave * 512;

#pragma unroll 2
    for (int it = 0; it < 8; ++it) {
        const int start = wavestart + it * 64;          // multiple of 64
        // all 64 px of this iteration share one window row
        const int srcbase = (cy0 + (start >> 7)) * 1024 + cx0 + (start & 127);
        const _Float16* pb = P + (size_t)(srcbase + sub) * 16 + quad * 4;

        float logit[4];
#pragma unroll
        for (int ch = 0; ch < 4; ++ch) {
            // chain ch: +16 px -> +256 elements -> 512B immediate offset
            half4 v = *(const half4*)(pb + ch * 256);
            half4 h = v - qh;
#pragma unroll
            for (int i = 0; i < 4; ++i)
                h[i] = h[i] > (_Float16)0.0f ? h[i] : (_Float16)0.0f;

            floatx4 c2 = __builtin_amdgcn_mfma_f32_16x16x16f16(a2, h, zero, 0, 0, 0);

            float part = 0.0f;
#pragma unroll
            for (int i = 0; i < 4; ++i)
                part = fmaf(w3f[i], fmaxf(c2[i] + bb2[i], 0.0f), part);
            part += __shfl_xor(part, 16, 64);
            part += __shfl_xor(part, 32, 64);
            logit[ch] = part;
        }

        const float l01 = (quad & 1) ? logit[1] : logit[0];
        const float l23 = (quad & 1) ? logit[3] : logit[2];
        const float lg  = (quad & 2) ? l23 : l01;
        const float prob = __builtin_amdgcn_rcpf(1.0f + __expf(-(lg + b3v)));

        out[cid * 16384 + start + lane] = prob;
    }
}

extern "C" void kernel_launch(void* const* d_in, const int* in_sizes, int n_in,
                              void* d_out, int out_size, void* d_ws, size_t ws_size,
                              hipStream_t stream) {
    const float* x     = (const float*)d_in[0];
    const float* sigma = (const float*)d_in[1];
    const float* c     = (const float*)d_in[2];
    const float* W1    = (const float*)d_in[3];
    const float* b1    = (const float*)d_in[4];
    const float* W2    = (const float*)d_in[5];
    const float* b2    = (const float*)d_in[6];
    const float* W3    = (const float*)d_in[7];
    const float* b3    = (const float*)d_in[8];
    const int*   cent  = (const int*)d_in[9];
    float* out = (float*)d_out;
    _Float16* P = (_Float16*)d_ws;   // 32 MB fp16 scratch

    prep<<<dim3(4096 + 2048), dim3(256), 0, stream>>>(x, sigma, W1, cent, P, out);
    instanseg_mlp<<<dim3(8, 512), dim3(256), 0, stream>>>(
        P, c, W1, b1, W2, b2, W3, b3, cent, out);
}